// Round 2
// baseline (47.743 us; speedup 1.0000x reference)
//
#include <hip/hip_runtime.h>
#include <math.h>

// Tropical (min-plus) matmul: out[b, j] = min_i (X[b, i] + W[j, i])
// X: [1024][512] fp32, W: [512][512] fp32, out: [1024][512] fp32.
//
// Strategy (round 2): NO LDS in the main loop.
//  - Prepass packs W into WT4[k4][j][4]  (k-major, 4-k groups contiguous per j)
//    so lane=j reads its W operand with one coalesced dwordx4 per 4 k (L2-hit).
//  - X is read at block-uniform addresses -> scalar/broadcast path (SGPR operand
//    in v_add_f32), zero LDS traffic, zero VGPR-lane bandwidth.
//  - Each lane: 4 m-accumulators; 2048 waves total = 2 waves/SIMD.
//  - min-chain written as fminf(fminf(a,t0),t1) to fuse into v_min3_f32.

#define B_DIM   1024
#define IN_DIM  512
#define OUT_DIM 512

// ---------------- prepass: WT4[k4][j] = { W[j][4k4..4k4+3] } ----------------
__global__ __launch_bounds__(256)
void MinPlus_wt4_pack(const float* __restrict__ W, float4* __restrict__ WT4) {
    __shared__ float Ls[64][68];   // 64x64 tile, padded rows (prepass: conflicts ok)
    const int tid = threadIdx.x;
    const int j0 = blockIdx.x * 64;
    const int k0 = blockIdx.y * 64;

#pragma unroll
    for (int r = 0; r < 4; ++r) {
        const int jj = (tid >> 4) + r * 16;
        const int kq = tid & 15;
        const float4 v = *reinterpret_cast<const float4*>(&W[(j0 + jj) * IN_DIM + k0 + 4 * kq]);
        *reinterpret_cast<float4*>(&Ls[jj][4 * kq]) = v;
    }
    __syncthreads();

    const int jj  = tid & 63;
    const int k4b = tid >> 6;      // 0..3
#pragma unroll
    for (int r = 0; r < 4; ++r) {
        const int k4l = r * 4 + k4b;                       // 0..15 within tile
        const float4 v = *reinterpret_cast<const float4*>(&Ls[jj][4 * k4l]);
        WT4[(size_t)(blockIdx.y * 16 + k4l) * OUT_DIM + j0 + jj] = v;
    }
}

// ---------------- main: lane = j, 4 m-rows per lane, no LDS ----------------
__global__ __launch_bounds__(256)
void MinPlus_70832600646269_kernel(const float* __restrict__ X,
                                   const float4* __restrict__ WT4,
                                   float* __restrict__ out)
{
    const int lane = threadIdx.x & 63;
    const int wid  = threadIdx.x >> 6;
    const int j    = blockIdx.x * 64 + lane;       // all 4 waves share j-range (L1 reuse of WT4)
    const int m0   = blockIdx.y * 16 + wid * 4;    // each wave owns 4 m-rows

    const float4* __restrict__ wp  = WT4 + j;      // stride OUT_DIM float4 per k4
    const float4* __restrict__ x0p = reinterpret_cast<const float4*>(X + (size_t)(m0 + 0) * IN_DIM);
    const float4* __restrict__ x1p = reinterpret_cast<const float4*>(X + (size_t)(m0 + 1) * IN_DIM);
    const float4* __restrict__ x2p = reinterpret_cast<const float4*>(X + (size_t)(m0 + 2) * IN_DIM);
    const float4* __restrict__ x3p = reinterpret_cast<const float4*>(X + (size_t)(m0 + 3) * IN_DIM);

    float a0 = INFINITY, a1 = INFINITY, a2 = INFINITY, a3 = INFINITY;

    // 1-deep prefetch: loads for k4+1 issued before computing k4
    float4 w  = wp[0];
    float4 x0 = x0p[0], x1 = x1p[0], x2 = x2p[0], x3 = x3p[0];

#pragma unroll 4
    for (int k4 = 0; k4 < (IN_DIM / 4) - 1; ++k4) {
        const float4 wn  = wp[(size_t)(k4 + 1) * OUT_DIM];
        const float4 xn0 = x0p[k4 + 1];
        const float4 xn1 = x1p[k4 + 1];
        const float4 xn2 = x2p[k4 + 1];
        const float4 xn3 = x3p[k4 + 1];

        a0 = fminf(fminf(a0, w.x + x0.x), w.y + x0.y);
        a0 = fminf(fminf(a0, w.z + x0.z), w.w + x0.w);
        a1 = fminf(fminf(a1, w.x + x1.x), w.y + x1.y);
        a1 = fminf(fminf(a1, w.z + x1.z), w.w + x1.w);
        a2 = fminf(fminf(a2, w.x + x2.x), w.y + x2.y);
        a2 = fminf(fminf(a2, w.z + x2.z), w.w + x2.w);
        a3 = fminf(fminf(a3, w.x + x3.x), w.y + x3.y);
        a3 = fminf(fminf(a3, w.z + x3.z), w.w + x3.w);

        w = wn; x0 = xn0; x1 = xn1; x2 = xn2; x3 = xn3;
    }

    // peeled last k4-step
    a0 = fminf(fminf(a0, w.x + x0.x), w.y + x0.y);
    a0 = fminf(fminf(a0, w.z + x0.z), w.w + x0.w);
    a1 = fminf(fminf(a1, w.x + x1.x), w.y + x1.y);
    a1 = fminf(fminf(a1, w.z + x1.z), w.w + x1.w);
    a2 = fminf(fminf(a2, w.x + x2.x), w.y + x2.y);
    a2 = fminf(fminf(a2, w.z + x2.z), w.w + x2.w);
    a3 = fminf(fminf(a3, w.x + x3.x), w.y + x3.y);
    a3 = fminf(fminf(a3, w.z + x3.z), w.w + x3.w);

    out[(size_t)(m0 + 0) * OUT_DIM + j] = a0;
    out[(size_t)(m0 + 1) * OUT_DIM + j] = a1;
    out[(size_t)(m0 + 2) * OUT_DIM + j] = a2;
    out[(size_t)(m0 + 3) * OUT_DIM + j] = a3;
}

extern "C" void kernel_launch(void* const* d_in, const int* in_sizes, int n_in,
                              void* d_out, int out_size, void* d_ws, size_t ws_size,
                              hipStream_t stream) {
    const float* X = (const float*)d_in[0];
    const float* W = (const float*)d_in[1];
    float* out = (float*)d_out;
    float4* WT4 = (float4*)d_ws;   // 128 * 512 float4 = 1 MiB

    // pack W -> WT4
    MinPlus_wt4_pack<<<dim3(OUT_DIM / 64, IN_DIM / 64), 256, 0, stream>>>(W, WT4);

    // main
    MinPlus_70832600646269_kernel<<<dim3(OUT_DIM / 64, B_DIM / 16), 256, 0, stream>>>(X, WT4, out);
}

// Round 4
// 22.627 us; speedup vs baseline: 2.1100x; 2.1100x over previous
//
#include <hip/hip_runtime.h>
#include <math.h>

// Tropical (min-plus) matmul: out[b, j] = min_i (X[b, i] + W[j, i])
// X: [1024][512] fp32, W: [512][512] fp32, out: [1024][512] fp32.
//
// Round 4 = round 3 + fix: X base pointer laundered through readfirstlane so
// it is provably wave-uniform -> lands in SGPR pair -> s_load_dwordx16 legal.
//
//  - W lane-resident: lane = j; each wave owns one 64-k chunk of W in 64 VGPRs,
//    loaded once per block from the packed WT4[k4][j] layout (coalesced).
//  - X wave-uniform: streamed through SGPRs via s_load_dwordx16 (scalar pipe;
//    v_add_f32 takes the SGPR operand directly). Software pipelined:
//    wait A / issue B / compute A / wait B / issue next A / compute B.
//  - 8 waves per block cover K=512; partial mins combined through LDS with a
//    single barrier. Grid 8x64 = 512 blocks = 2 blocks/CU, 16 waves/CU.

#define B_DIM   1024
#define IN_DIM  512
#define OUT_DIM 512

typedef float f16v __attribute__((ext_vector_type(16)));

// ---------------- prepass: WT4[k4][j] = { W[j][4k4..4k4+3] } ----------------
__global__ __launch_bounds__(256)
void MinPlus_wt4_pack(const float* __restrict__ W, float4* __restrict__ WT4) {
    __shared__ float Ls[64][68];
    const int tid = threadIdx.x;
    const int j0 = blockIdx.x * 64;
    const int k0 = blockIdx.y * 64;

#pragma unroll
    for (int r = 0; r < 4; ++r) {
        const int jj = (tid >> 4) + r * 16;
        const int kq = tid & 15;
        const float4 v = *reinterpret_cast<const float4*>(&W[(j0 + jj) * IN_DIM + k0 + 4 * kq]);
        *reinterpret_cast<float4*>(&Ls[jj][4 * kq]) = v;
    }
    __syncthreads();

    const int jj  = tid & 63;
    const int k4b = tid >> 6;
#pragma unroll
    for (int r = 0; r < 4; ++r) {
        const int k4l = r * 4 + k4b;
        const float4 v = *reinterpret_cast<const float4*>(&Ls[jj][4 * k4l]);
        WT4[(size_t)(blockIdx.y * 16 + k4l) * OUT_DIM + j0 + jj] = v;
    }
}

// ---------------- main ----------------
__global__ __launch_bounds__(512)
void MinPlus_70832600646269_kernel(const float* __restrict__ X,
                                   const float4* __restrict__ WT4,
                                   float* __restrict__ out)
{
    __shared__ float part[8][16][64];   // [wave(k-chunk)][b][j-lane]

    const int tid  = threadIdx.x;
    const int lane = tid & 63;
    const int wid  = tid >> 6;          // 0..7 = k-chunk id (wave-uniform)
    const int j0   = blockIdx.x * 64;
    const int b0   = blockIdx.y * 16;

    // ---- W chunk -> 64 VGPRs (once). wr[q] = W[j0+lane][wid*64 + 4q .. +3] ----
    float4 wr[16];
#pragma unroll
    for (int q = 0; q < 16; ++q)
        wr[q] = WT4[(size_t)(wid * 16 + q) * OUT_DIM + j0 + lane];

    // ---- wave-uniform X base in an SGPR pair ----
    const uint64_t xaddr = (uint64_t)(X + (size_t)b0 * IN_DIM + wid * 64);
    const uint32_t xlo = __builtin_amdgcn_readfirstlane((uint32_t)xaddr);
    const uint32_t xhi = __builtin_amdgcn_readfirstlane((uint32_t)(xaddr >> 32));
    const uint64_t sbase = ((uint64_t)xhi << 32) | xlo;

    f16v xa0, xa1, xb0, xb1;
    // prologue: issue A-half of b=0 (k 0..31 of this chunk)
    asm volatile("s_load_dwordx16 %0, %2, 0x0\n\t"
                 "s_load_dwordx16 %1, %2, 0x40"
                 : "=&s"(xa0), "=&s"(xa1) : "s"(sbase));

    for (int b = 0; b < 16; ++b) {
        const uint64_t sb  = sbase + (uint64_t)b * (IN_DIM * 4);
        const uint64_t sbn = sb + (IN_DIM * 4);

        float acc[4];
#pragma unroll
        for (int c = 0; c < 4; ++c) acc[c] = INFINITY;

        // wait A ready (ties create the ordering dep)
        asm volatile("s_waitcnt lgkmcnt(0)" : "+s"(xa0), "+s"(xa1));
        // issue B-half (k 32..63)
        asm volatile("s_load_dwordx16 %0, %2, 0x80\n\t"
                     "s_load_dwordx16 %1, %2, 0xc0"
                     : "=&s"(xb0), "=&s"(xb1) : "s"(sb));

        // ---- compute A half: k = 0..31 ----
#pragma unroll
        for (int q = 0; q < 4; ++q) {
            const float4 wq = wr[q];
            const float t0 = wq.x + xa0[4 * q + 0];
            const float t1 = wq.y + xa0[4 * q + 1];
            const float t2 = wq.z + xa0[4 * q + 2];
            const float t3 = wq.w + xa0[4 * q + 3];
            acc[q] = fminf(fminf(acc[q], t0), t1);   // v_min3
            acc[q] = fminf(fminf(acc[q], t2), t3);   // v_min3
        }
#pragma unroll
        for (int q = 0; q < 4; ++q) {
            const float4 wq = wr[4 + q];
            const float t0 = wq.x + xa1[4 * q + 0];
            const float t1 = wq.y + xa1[4 * q + 1];
            const float t2 = wq.z + xa1[4 * q + 2];
            const float t3 = wq.w + xa1[4 * q + 3];
            acc[q] = fminf(fminf(acc[q], t0), t1);
            acc[q] = fminf(fminf(acc[q], t2), t3);
        }

        // wait B ready
        asm volatile("s_waitcnt lgkmcnt(0)" : "+s"(xb0), "+s"(xb1));
        // issue next b's A-half (guard the tail: no OOB s_load)
        if (b < 15) {
            asm volatile("s_load_dwordx16 %0, %2, 0x0\n\t"
                         "s_load_dwordx16 %1, %2, 0x40"
                         : "=&s"(xa0), "=&s"(xa1) : "s"(sbn));
        }

        // ---- compute B half: k = 32..63 ----
#pragma unroll
        for (int q = 0; q < 4; ++q) {
            const float4 wq = wr[8 + q];
            const float t0 = wq.x + xb0[4 * q + 0];
            const float t1 = wq.y + xb0[4 * q + 1];
            const float t2 = wq.z + xb0[4 * q + 2];
            const float t3 = wq.w + xb0[4 * q + 3];
            acc[q] = fminf(fminf(acc[q], t0), t1);
            acc[q] = fminf(fminf(acc[q], t2), t3);
        }
#pragma unroll
        for (int q = 0; q < 4; ++q) {
            const float4 wq = wr[12 + q];
            const float t0 = wq.x + xb1[4 * q + 0];
            const float t1 = wq.y + xb1[4 * q + 1];
            const float t2 = wq.z + xb1[4 * q + 2];
            const float t3 = wq.w + xb1[4 * q + 3];
            acc[q] = fminf(fminf(acc[q], t0), t1);
            acc[q] = fminf(fminf(acc[q], t2), t3);
        }

        const float m = fminf(fminf(fminf(acc[0], acc[1]), acc[2]), acc[3]);
        part[wid][b][lane] = m;
    }

    __syncthreads();

    // ---- combine 8 k-chunks; wave wid handles b = 2*wid, 2*wid+1 ----
#pragma unroll
    for (int r = 0; r < 2; ++r) {
        const int b = wid * 2 + r;
        float m = part[0][b][lane];
#pragma unroll
        for (int p = 1; p < 8; ++p) m = fminf(m, part[p][b][lane]);
        out[(size_t)(b0 + b) * OUT_DIM + j0 + lane] = m;
    }
}

extern "C" void kernel_launch(void* const* d_in, const int* in_sizes, int n_in,
                              void* d_out, int out_size, void* d_ws, size_t ws_size,
                              hipStream_t stream) {
    const float* X = (const float*)d_in[0];
    const float* W = (const float*)d_in[1];
    float* out = (float*)d_out;
    float4* WT4 = (float4*)d_ws;   // 128 * 512 float4 = 1 MiB

    MinPlus_wt4_pack<<<dim3(OUT_DIM / 64, IN_DIM / 64), 256, 0, stream>>>(W, WT4);

    MinPlus_70832600646269_kernel<<<dim3(OUT_DIM / 64, B_DIM / 16), 512, 0, stream>>>(X, WT4, out);
}